// Round 11
// baseline (54.044 us; speedup 1.0000x reference)
//
#include <hip/hip_runtime.h>
#include <math.h>

constexpr int NB    = 128;
constexpr int NPAIR = NB * (NB - 1) / 2;        // 8128
constexpr int NANG  = NB - 2;                   // 126
constexpr int NDIH  = NB - 3;                   // 125
constexpr int ROW   = NPAIR + NANG + 2 * NDIH;  // 8504

// R9 structure (best: 31.3us) + NONTEMPORAL stores: output is write-once,
// never re-read -> stream past L2 (nt) so lines drain to HBM in issue order
// instead of lingering until capacity eviction.
__global__ __launch_bounds__(1024, 8) void protein_feat_kernel(
        const float* __restrict__ data, float* __restrict__ out) {
    __shared__ float4 s4[NB];                    // (x,y,z,0) per bead
    const int b  = blockIdx.x;
    const int t  = threadIdx.x;                  // 0..1023
    const int tb = t & 127;                      // bead index
    const int g  = t >> 7;                       // off-group 0..7 (wave-uniform)
    const float* src = data + (size_t)b * (NB * 3);

    if (t < NB)
        s4[t] = make_float4(src[3 * t], src[3 * t + 1], src[3 * t + 2], 0.0f);
    __syncthreads();

    float* orow = out + (size_t)b * ROW;

    // Register band: lane holds beads tb, tb-1, tb-2, tb-3.
    float px[4], py[4], pz[4];
    #pragma unroll
    for (int k = 0; k < 4; ++k) {
        int idx = tb - k; if (idx < 0) idx = 0;  // clamped; masked at store
        float4 v = s4[idx];
        px[k] = v.x; py[k] = v.y; pz[k] = v.z;
    }

    // ---- Distances: group g handles off = 1+4g+32m (m=0..3), 4 rows per
    // ds_read_b128 (conflict-free reads, stride-1 coalesced nt stores).
    #pragma unroll
    for (int m = 0; m < 4; ++m) {
        const int off = 1 + 4 * g + 32 * m;
        const int len = NB - off;
        const int bk0 = (off - 1) * (2 * NB - off) / 2;  // B(off)
        const int bk1 = bk0 + len;
        const int bk2 = bk1 + len - 1;
        const int bk3 = bk2 + len - 2;
        if (tb < len) {                          // upper wave execz-skips len<=64
            float4 pj = s4[tb + off];
            float dx, dy, dz, d;
            dx = pj.x - px[0]; dy = pj.y - py[0]; dz = pj.z - pz[0];
            d = __builtin_amdgcn_sqrtf(dx*dx + dy*dy + dz*dz);
            __builtin_nontemporal_store(d, &orow[bk0 + tb]);
            dx = pj.x - px[1]; dy = pj.y - py[1]; dz = pj.z - pz[1];
            d = __builtin_amdgcn_sqrtf(dx*dx + dy*dy + dz*dz);
            if (tb >= 1) __builtin_nontemporal_store(d, &orow[bk1 + tb - 1]);
            dx = pj.x - px[2]; dy = pj.y - py[2]; dz = pj.z - pz[2];
            d = __builtin_amdgcn_sqrtf(dx*dx + dy*dy + dz*dz);
            if (tb >= 2) __builtin_nontemporal_store(d, &orow[bk2 + tb - 2]);
            dx = pj.x - px[3]; dy = pj.y - py[3]; dz = pj.z - pz[3];
            d = __builtin_amdgcn_sqrtf(dx*dx + dy*dy + dz*dz);
            if (tb >= 3) __builtin_nontemporal_store(d, &orow[bk3 + tb - 3]);
        }
    }

    // ---- Angles (126) + dihedral cos (125) + dihedral sin (125): t<376 only.
    const int v = t;
    if (v < NANG + 2 * NDIH) {
        if (v < NANG) {
            int a = v;
            float4 p0 = s4[a], p1 = s4[a + 1], p2 = s4[a + 2];
            float a0x = p1.x - p0.x, a0y = p1.y - p0.y, a0z = p1.z - p0.z;
            float a1x = p2.x - p1.x, a1y = p2.y - p1.y, a1z = p2.z - p1.z;
            float d  = a0x * a1x + a0y * a1y + a0z * a1z;
            float r0 = rsqrtf(a0x * a0x + a0y * a0y + a0z * a0z);
            float r1 = rsqrtf(a1x * a1x + a1y * a1y + a1z * a1z);
            float c  = d * r0 * r1;
            c = fminf(1.0f, fmaxf(-1.0f, c));
            __builtin_nontemporal_store(acosf(c), &orow[NPAIR + a]);
        } else {
            int a = (v < NANG + NDIH) ? (v - NANG) : (v - NANG - NDIH);
            float4 p0 = s4[a], p1 = s4[a + 1], p2 = s4[a + 2], p3 = s4[a + 3];
            float e0x = p1.x - p0.x, e0y = p1.y - p0.y, e0z = p1.z - p0.z;
            float e1x = p2.x - p1.x, e1y = p2.y - p1.y, e1z = p2.z - p1.z;
            float e2x = p3.x - p2.x, e2y = p3.y - p2.y, e2z = p3.z - p2.z;
            float c0x = e0y * e1z - e0z * e1y;
            float c0y = e0z * e1x - e0x * e1z;
            float c0z = e0x * e1y - e0y * e1x;
            float c1x = e1y * e2z - e1z * e2y;
            float c1y = e1z * e2x - e1x * e2z;
            float c1z = e1x * e2y - e1y * e2x;
            float rn0 = rsqrtf(c0x * c0x + c0y * c0y + c0z * c0z);
            if (v < NANG + NDIH) {
                float d   = c0x * c1x + c0y * c1y + c0z * c1z;
                float rn1 = rsqrtf(c1x * c1x + c1y * c1y + c1z * c1z);
                __builtin_nontemporal_store(d * rn0 * rn1, &orow[NPAIR + NANG + a]);
            } else {
                float qx = c1y * e1z - c1z * e1y;   // plane = c1 x e1
                float qy = c1z * e1x - c1x * e1z;
                float qz = c1x * e1y - c1y * e1x;
                float d  = c0x * qx + c0y * qy + c0z * qz;
                float rp = rsqrtf(qx * qx + qy * qy + qz * qz);
                __builtin_nontemporal_store(d * rn0 * rp,
                                            &orow[NPAIR + NANG + NDIH + a]);
            }
        }
    }
}

extern "C" void kernel_launch(void* const* d_in, const int* in_sizes, int n_in,
                              void* d_out, int out_size, void* d_ws, size_t ws_size,
                              hipStream_t stream) {
    const float* data = (const float*)d_in[0];
    float* out = (float*)d_out;
    const int batch = in_sizes[0] / (NB * 3);   // 4096
    protein_feat_kernel<<<batch, 1024, 0, stream>>>(data, out);
}

// Round 12
// 53.568 us; speedup vs baseline: 1.0089x; 1.0089x over previous
//
#include <hip/hip_runtime.h>
#include <math.h>

constexpr int NB    = 128;
constexpr int NPAIR = NB * (NB - 1) / 2;        // 8128
constexpr int NANG  = NB - 2;                   // 126
constexpr int NDIH  = NB - 3;                   // 125
constexpr int ROW   = NPAIR + NANG + 2 * NDIH;  // 8504
constexpr int PPB   = 8;                         // proteins per persistent block

// Persistent 1024-thr blocks (2/CU, 32 waves/CU), 8 proteins each, with
// double-buffered LDS staging: protein n+1's coords are global-loaded and
// ds_written during protein n's compute -> stage latency off critical path.
__global__ __launch_bounds__(1024, 8) void protein_feat_kernel(
        const float* __restrict__ data, float* __restrict__ out) {
    __shared__ float4 s4[2][NB];                 // double-buffered coords
    const int t  = threadIdx.x;                  // 0..1023
    const int tb = t & 127;                      // bead index
    const int g  = t >> 7;                       // off-group 0..7 (wave-uniform)
    const int p0 = blockIdx.x * PPB;

    // Prologue: stage protein p0 into s4[0].
    if (t < NB) {
        const float* s = data + (size_t)p0 * (NB * 3) + 3 * t;
        s4[0][t] = make_float4(s[0], s[1], s[2], 0.0f);
    }
    __syncthreads();

    int cur = 0;
    for (int it = 0; it < PPB; ++it) {
        const int p = p0 + it;

        // Prefetch next protein's coords into registers (latency hidden
        // under this protein's compute; ds_write happens at iteration end).
        float nx = 0.f, ny = 0.f, nz = 0.f;
        const bool pf = (t < NB) && (it + 1 < PPB);
        if (pf) {
            const float* s = data + (size_t)(p + 1) * (NB * 3) + 3 * t;
            nx = s[0]; ny = s[1]; nz = s[2];
        }

        float* orow = out + (size_t)p * ROW;

        // Register band: lane holds beads tb, tb-1, tb-2, tb-3.
        float px[4], py[4], pz[4];
        #pragma unroll
        for (int k = 0; k < 4; ++k) {
            int idx = tb - k; if (idx < 0) idx = 0;   // clamped; masked at store
            float4 v = s4[cur][idx];
            px[k] = v.x; py[k] = v.y; pz[k] = v.z;
        }

        // ---- Distances: group g handles off = 1+4g+32m (m=0..3), 4 rows per
        // ds_read_b128 (conflict-free reads, stride-1 coalesced stores).
        #pragma unroll
        for (int m = 0; m < 4; ++m) {
            const int off = 1 + 4 * g + 32 * m;
            const int len = NB - off;
            const int bk0 = (off - 1) * (2 * NB - off) / 2;  // B(off)
            const int bk1 = bk0 + len;
            const int bk2 = bk1 + len - 1;
            const int bk3 = bk2 + len - 2;
            if (tb < len) {                      // upper waves execz-skip len<=64
                float4 pj = s4[cur][tb + off];
                float dx, dy, dz, d;
                dx = pj.x - px[0]; dy = pj.y - py[0]; dz = pj.z - pz[0];
                d = __builtin_amdgcn_sqrtf(dx*dx + dy*dy + dz*dz);
                orow[bk0 + tb] = d;
                dx = pj.x - px[1]; dy = pj.y - py[1]; dz = pj.z - pz[1];
                d = __builtin_amdgcn_sqrtf(dx*dx + dy*dy + dz*dz);
                if (tb >= 1) orow[bk1 + tb - 1] = d;
                dx = pj.x - px[2]; dy = pj.y - py[2]; dz = pj.z - pz[2];
                d = __builtin_amdgcn_sqrtf(dx*dx + dy*dy + dz*dz);
                if (tb >= 2) orow[bk2 + tb - 2] = d;
                dx = pj.x - px[3]; dy = pj.y - py[3]; dz = pj.z - pz[3];
                d = __builtin_amdgcn_sqrtf(dx*dx + dy*dy + dz*dz);
                if (tb >= 3) orow[bk3 + tb - 3] = d;
            }
        }

        // ---- Angles (126) + dihedral cos (125) + dihedral sin (125).
        if (t < NANG + 2 * NDIH) {
            const int v = t;
            if (v < NANG) {
                int a = v;
                float4 q0 = s4[cur][a], q1 = s4[cur][a+1], q2 = s4[cur][a+2];
                float a0x = q1.x - q0.x, a0y = q1.y - q0.y, a0z = q1.z - q0.z;
                float a1x = q2.x - q1.x, a1y = q2.y - q1.y, a1z = q2.z - q1.z;
                float d  = a0x * a1x + a0y * a1y + a0z * a1z;
                float r0 = rsqrtf(a0x * a0x + a0y * a0y + a0z * a0z);
                float r1 = rsqrtf(a1x * a1x + a1y * a1y + a1z * a1z);
                float c  = d * r0 * r1;
                c = fminf(1.0f, fmaxf(-1.0f, c));
                orow[NPAIR + a] = acosf(c);
            } else {
                int a = (v < NANG + NDIH) ? (v - NANG) : (v - NANG - NDIH);
                float4 q0 = s4[cur][a],   q1 = s4[cur][a+1];
                float4 q2 = s4[cur][a+2], q3 = s4[cur][a+3];
                float e0x = q1.x - q0.x, e0y = q1.y - q0.y, e0z = q1.z - q0.z;
                float e1x = q2.x - q1.x, e1y = q2.y - q1.y, e1z = q2.z - q1.z;
                float e2x = q3.x - q2.x, e2y = q3.y - q2.y, e2z = q3.z - q2.z;
                float c0x = e0y * e1z - e0z * e1y;
                float c0y = e0z * e1x - e0x * e1z;
                float c0z = e0x * e1y - e0y * e1x;
                float c1x = e1y * e2z - e1z * e2y;
                float c1y = e1z * e2x - e1x * e2z;
                float c1z = e1x * e2y - e1y * e2x;
                float rn0 = rsqrtf(c0x * c0x + c0y * c0y + c0z * c0z);
                if (v < NANG + NDIH) {
                    float d   = c0x * c1x + c0y * c1y + c0z * c1z;
                    float rn1 = rsqrtf(c1x * c1x + c1y * c1y + c1z * c1z);
                    orow[NPAIR + NANG + a] = d * rn0 * rn1;
                } else {
                    float qx = c1y * e1z - c1z * e1y;   // plane = c1 x e1
                    float qy = c1z * e1x - c1x * e1z;
                    float qz = c1x * e1y - c1y * e1x;
                    float d  = c0x * qx + c0y * qy + c0z * qz;
                    float rp = rsqrtf(qx * qx + qy * qy + qz * qz);
                    orow[NPAIR + NANG + NDIH + a] = d * rn0 * rp;
                }
            }
        }

        // Write prefetched coords to the other buffer; one barrier per iter.
        if (pf) s4[cur ^ 1][t] = make_float4(nx, ny, nz, 0.0f);
        __syncthreads();
        cur ^= 1;
    }
}

extern "C" void kernel_launch(void* const* d_in, const int* in_sizes, int n_in,
                              void* d_out, int out_size, void* d_ws, size_t ws_size,
                              hipStream_t stream) {
    const float* data = (const float*)d_in[0];
    float* out = (float*)d_out;
    const int batch = in_sizes[0] / (NB * 3);   // 4096
    protein_feat_kernel<<<batch / PPB, 1024, 0, stream>>>(data, out);
}

// Round 13
// 30.779 us; speedup vs baseline: 1.7559x; 1.7404x over previous
//
#include <hip/hip_runtime.h>
#include <math.h>

constexpr int NB    = 128;
constexpr int NPAIR = NB * (NB - 1) / 2;        // 8128
constexpr int NANG  = NB - 2;                   // 126
constexpr int NDIH  = NB - 3;                   // 125
constexpr int ROW   = NPAIR + NANG + 2 * NDIH;  // 8504

// R9 structure, ONE change: group g owns the CONTIGUOUS off-band
// 16g+1..16g+16 (off = 16g+4m+1, bands of 4), so each group's stores form a
// contiguous in-order sub-stream of the protein's output region (DRAM write
// locality), instead of R9's 32 interleaved bands.
__global__ __launch_bounds__(1024, 8) void protein_feat_kernel(
        const float* __restrict__ data, float* __restrict__ out) {
    __shared__ float4 s4[NB];                    // (x,y,z,0) per bead
    const int b  = blockIdx.x;
    const int t  = threadIdx.x;                  // 0..1023
    const int tb = t & 127;                      // bead index
    const int g  = t >> 7;                       // off-group 0..7 (wave-uniform)
    const float* src = data + (size_t)b * (NB * 3);

    if (t < NB)
        s4[t] = make_float4(src[3 * t], src[3 * t + 1], src[3 * t + 2], 0.0f);
    __syncthreads();

    float* orow = out + (size_t)b * ROW;

    // Register band: lane holds beads tb, tb-1, tb-2, tb-3.
    float px[4], py[4], pz[4];
    #pragma unroll
    for (int k = 0; k < 4; ++k) {
        int idx = tb - k; if (idx < 0) idx = 0;  // clamped; masked at store
        float4 v = s4[idx];
        px[k] = v.x; py[k] = v.y; pz[k] = v.z;
    }

    // ---- Distances: group g handles off = 16g+4m+1 (m=0..3) -> contiguous
    // off-band 16g+1..16g+16; 4 rows per ds_read_b128 (conflict-free reads,
    // stride-1 coalesced stores advancing in address order per group).
    #pragma unroll
    for (int m = 0; m < 4; ++m) {
        const int off = 16 * g + 4 * m + 1;
        const int len = NB - off;
        const int bk0 = (off - 1) * (2 * NB - off) / 2;  // B(off)
        const int bk1 = bk0 + len;
        const int bk2 = bk1 + len - 1;
        const int bk3 = bk2 + len - 2;
        if (tb < len) {                          // high groups mostly execz-skip
            float4 pj = s4[tb + off];
            float dx, dy, dz, d;
            dx = pj.x - px[0]; dy = pj.y - py[0]; dz = pj.z - pz[0];
            d = __builtin_amdgcn_sqrtf(dx*dx + dy*dy + dz*dz);
            orow[bk0 + tb] = d;
            dx = pj.x - px[1]; dy = pj.y - py[1]; dz = pj.z - pz[1];
            d = __builtin_amdgcn_sqrtf(dx*dx + dy*dy + dz*dz);
            if (tb >= 1) orow[bk1 + tb - 1] = d;
            dx = pj.x - px[2]; dy = pj.y - py[2]; dz = pj.z - pz[2];
            d = __builtin_amdgcn_sqrtf(dx*dx + dy*dy + dz*dz);
            if (tb >= 2) orow[bk2 + tb - 2] = d;
            dx = pj.x - px[3]; dy = pj.y - py[3]; dz = pj.z - pz[3];
            d = __builtin_amdgcn_sqrtf(dx*dx + dy*dy + dz*dz);
            if (tb >= 3) orow[bk3 + tb - 3] = d;
        }
    }

    // ---- Angles (126) + dihedral cos (125) + dihedral sin (125): t<376 only.
    const int v = t;
    if (v < NANG + 2 * NDIH) {
        if (v < NANG) {
            int a = v;
            float4 p0 = s4[a], p1 = s4[a + 1], p2 = s4[a + 2];
            float a0x = p1.x - p0.x, a0y = p1.y - p0.y, a0z = p1.z - p0.z;
            float a1x = p2.x - p1.x, a1y = p2.y - p1.y, a1z = p2.z - p1.z;
            float d  = a0x * a1x + a0y * a1y + a0z * a1z;
            float r0 = rsqrtf(a0x * a0x + a0y * a0y + a0z * a0z);
            float r1 = rsqrtf(a1x * a1x + a1y * a1y + a1z * a1z);
            float c  = d * r0 * r1;
            c = fminf(1.0f, fmaxf(-1.0f, c));
            orow[NPAIR + a] = acosf(c);
        } else {
            int a = (v < NANG + NDIH) ? (v - NANG) : (v - NANG - NDIH);
            float4 p0 = s4[a], p1 = s4[a + 1], p2 = s4[a + 2], p3 = s4[a + 3];
            float e0x = p1.x - p0.x, e0y = p1.y - p0.y, e0z = p1.z - p0.z;
            float e1x = p2.x - p1.x, e1y = p2.y - p1.y, e1z = p2.z - p1.z;
            float e2x = p3.x - p2.x, e2y = p3.y - p2.y, e2z = p3.z - p2.z;
            float c0x = e0y * e1z - e0z * e1y;
            float c0y = e0z * e1x - e0x * e1z;
            float c0z = e0x * e1y - e0y * e1x;
            float c1x = e1y * e2z - e1z * e2y;
            float c1y = e1z * e2x - e1x * e2z;
            float c1z = e1x * e2y - e1y * e2x;
            float rn0 = rsqrtf(c0x * c0x + c0y * c0y + c0z * c0z);
            if (v < NANG + NDIH) {
                float d   = c0x * c1x + c0y * c1y + c0z * c1z;
                float rn1 = rsqrtf(c1x * c1x + c1y * c1y + c1z * c1z);
                orow[NPAIR + NANG + a] = d * rn0 * rn1;
            } else {
                float qx = c1y * e1z - c1z * e1y;   // plane = c1 x e1
                float qy = c1z * e1x - c1x * e1z;
                float qz = c1x * e1y - c1y * e1x;
                float d  = c0x * qx + c0y * qy + c0z * qz;
                float rp = rsqrtf(qx * qx + qy * qy + qz * qz);
                orow[NPAIR + NANG + NDIH + a] = d * rn0 * rp;
            }
        }
    }
}

extern "C" void kernel_launch(void* const* d_in, const int* in_sizes, int n_in,
                              void* d_out, int out_size, void* d_ws, size_t ws_size,
                              hipStream_t stream) {
    const float* data = (const float*)d_in[0];
    float* out = (float*)d_out;
    const int batch = in_sizes[0] / (NB * 3);   // 4096
    protein_feat_kernel<<<batch, 1024, 0, stream>>>(data, out);
}